// Round 2
// baseline (361.012 us; speedup 1.0000x reference)
//
#include <hip/hip_runtime.h>

// sigma = 1e-4  ->  1/sigma = 1e4
#define INV_SIGMA 1.0e4f

__device__ __forceinline__ float one_minus_prob(float d, int f) {
    // factor = (f >= 0) ? (1 - sigmoid(-d/sigma)) : 1
    //        = (f >= 0) ? sigmoid(d/sigma)        : 1
    float s = 1.0f / (1.0f + __expf(-d * INV_SIGMA));
    return (f >= 0) ? s : 1.0f;
}

// Layout: K=16 floats per pixel = 4 float4 "chunks" per pixel.
// Lane-transposed: chunk c = 4*pixel + j is loaded by consecutive lanes, so
// every dwordx4 load is 64 lanes x 16B contiguous (16 fully-used 64B lines),
// instead of the 64-line strided pattern of one-thread-per-pixel.
// Product across the 4 chunks of a pixel: width-4 shuffle butterfly.
// Output: out float index == chunk index (4p+j), so stores are coalesced too.
__global__ __launch_bounds__(256) void SelfShader_9921374454199_kernel(
    const float* __restrict__ zbuf,
    const float* __restrict__ dists,
    const int*   __restrict__ p2f,
    float*       __restrict__ out,
    long long nChunks)  // 4 * N*H*W
{
    const float4* d4 = reinterpret_cast<const float4*>(dists);
    const int4*   f4 = reinterpret_cast<const int4*>(p2f);
    const float4* z4 = reinterpret_cast<const float4*>(zbuf);

    int t = threadIdx.x;
    int j = t & 3;  // which quarter of the pixel this lane owns
    long long cbase = (long long)blockIdx.x * 1024 + t;  // 4 rounds x 256 chunks

#pragma unroll
    for (int r = 0; r < 4; ++r) {
        long long c = cbase + r * 256;
        if (c >= nChunks) break;

        float4 d = d4[c];
        int4   f = f4[c];
        float  z = z4[c].x;  // only meaningful on j==0 lanes (zbuf[p*16])

        float prod = one_minus_prob(d.x, f.x) * one_minus_prob(d.y, f.y) *
                     one_minus_prob(d.z, f.z) * one_minus_prob(d.w, f.w);

        // combine the 4 quarter-products of this pixel (lanes 4k..4k+3)
        prod *= __shfl_xor(prod, 1, 4);
        prod *= __shfl_xor(prod, 2, 4);

        float zz = __shfl(z, 0, 4);  // broadcast z from the j==0 lane

        out[c] = (j == 3) ? (1.0f - prod) : zz;
    }
}

extern "C" void kernel_launch(void* const* d_in, const int* in_sizes, int n_in,
                              void* d_out, int out_size, void* d_ws, size_t ws_size,
                              hipStream_t stream) {
    const float* zbuf  = (const float*)d_in[0];
    const float* dists = (const float*)d_in[1];
    const int*   p2f   = (const int*)d_in[2];
    float*       out   = (float*)d_out;

    long long nChunks = (long long)in_sizes[0] / 4;  // 4 chunks per pixel, K=16
    int  block = 256;
    long long chunksPerBlock = 1024;
    int  grid = (int)((nChunks + chunksPerBlock - 1) / chunksPerBlock);
    SelfShader_9921374454199_kernel<<<grid, block, 0, stream>>>(zbuf, dists, p2f, out, nChunks);
}

// Round 4
// 334.006 us; speedup vs baseline: 1.0809x; 1.0809x over previous
//
#include <hip/hip_runtime.h>

// sigma = 1e-4  ->  1/sigma = 1e4
#define INV_SIGMA 1.0e4f
#define ROUNDS 8   // chunks per thread; 256 threads * 8 = 2048 chunks/block

typedef float v4f __attribute__((ext_vector_type(4)));
typedef int   v4i __attribute__((ext_vector_type(4)));

__device__ __forceinline__ float one_minus_prob(float d, int f) {
    // (f >= 0) ? 1 - sigmoid(-d/sigma) : 1   ==   (f >= 0) ? sigmoid(d/sigma) : 1
    float s = 1.0f / (1.0f + __expf(-d * INV_SIGMA));
    return (f >= 0) ? s : 1.0f;
}

// Chunk-transposed layout (chunk = float4 quarter-pixel), coalesced per
// instruction, PLUS all ROUNDS loads hoisted ahead of any use so each wave
// keeps ~24 vmem loads in flight instead of 3 (R2's per-round break gated
// loads behind a branch -> round-serial vmcnt(0) waits).
// Nontemporal: three 128 MiB streams + 32 MiB out shouldn't allocate in LLC.
__global__ __launch_bounds__(256) void SelfShader_9921374454199_kernel(
    const float* __restrict__ zbuf,
    const float* __restrict__ dists,
    const int*   __restrict__ p2f,
    float*       __restrict__ out,
    long long nChunks)  // 4 * N*H*W
{
    const int t = threadIdx.x;
    const long long cbase = (long long)blockIdx.x * (256 * ROUNDS) + t;

    const v4f* d4 = reinterpret_cast<const v4f*>(dists);
    const v4i* f4 = reinterpret_cast<const v4i*>(p2f);

    if (cbase + (ROUNDS - 1) * 256 < nChunks) {
        v4f   d[ROUNDS];
        v4i   f[ROUNDS];
        float z[ROUNDS];
#pragma unroll
        for (int r = 0; r < ROUNDS; ++r) {
            long long c = cbase + r * 256;
            d[r] = __builtin_nontemporal_load(d4 + c);
            f[r] = __builtin_nontemporal_load(f4 + c);
            // zbuf[pixel*16], pixel = c>>2; 4 lanes share an address (coalesces)
            z[r] = __builtin_nontemporal_load(zbuf + ((c >> 2) << 4));
        }
#pragma unroll
        for (int r = 0; r < ROUNDS; ++r) {
            long long c = cbase + r * 256;
            float prod = one_minus_prob(d[r].x, f[r].x) * one_minus_prob(d[r].y, f[r].y)
                       * one_minus_prob(d[r].z, f[r].z) * one_minus_prob(d[r].w, f[r].w);
            // combine the 4 quarter-products of this pixel (lanes 4k..4k+3)
            prod *= __shfl_xor(prod, 1, 4);
            prod *= __shfl_xor(prod, 2, 4);
            float v = ((t & 3) == 3) ? (1.0f - prod) : z[r];
            __builtin_nontemporal_store(v, out + c);
        }
    } else {
        // tail path (never taken for the bench shape: 8.39M chunks / 2048 exact)
        for (int r = 0; r < ROUNDS; ++r) {
            long long c = cbase + r * 256;
            if (c >= nChunks) break;
            v4f   dd = d4[c];
            v4i   ff = f4[c];
            float zz = zbuf[(c >> 2) << 4];
            float prod = one_minus_prob(dd.x, ff.x) * one_minus_prob(dd.y, ff.y)
                       * one_minus_prob(dd.z, ff.z) * one_minus_prob(dd.w, ff.w);
            prod *= __shfl_xor(prod, 1, 4);
            prod *= __shfl_xor(prod, 2, 4);
            out[c] = ((t & 3) == 3) ? (1.0f - prod) : zz;
        }
    }
}

extern "C" void kernel_launch(void* const* d_in, const int* in_sizes, int n_in,
                              void* d_out, int out_size, void* d_ws, size_t ws_size,
                              hipStream_t stream) {
    const float* zbuf  = (const float*)d_in[0];
    const float* dists = (const float*)d_in[1];
    const int*   p2f   = (const int*)d_in[2];
    float*       out   = (float*)d_out;

    long long nChunks = (long long)in_sizes[0] / 4;  // 4 float4 chunks per pixel (K=16)
    const long long chunksPerBlock = 256LL * ROUNDS;
    int grid = (int)((nChunks + chunksPerBlock - 1) / chunksPerBlock);
    SelfShader_9921374454199_kernel<<<grid, 256, 0, stream>>>(zbuf, dists, p2f, out, nChunks);
}